// Round 6
// baseline (6980.206 us; speedup 1.0000x reference)
//
#include <hip/hip_runtime.h>
#include <hip/hip_bf16.h>
#include <stdint.h>

#define L_SEQ 200
#define DIN_PAD 320   // 303 padded to 320; only first 300 (emb) nonzero in bf16 path

using short8  = __attribute__((ext_vector_type(8))) short;
using float4v = __attribute__((ext_vector_type(4))) float;

struct U2 { unsigned x, y; };

// k-slot mapping within a 32-wide K slice for mfma_f32_16x16x32_bf16 operands.
// Applied identically to A and B operands, so correctness is invariant to the
// exact hw intra-slice permutation (A/B layouts are symmetric).
#define KOFF(g,i) (((i)&3) + 4*(g) + 16*((i)>>2))

__device__ __forceinline__ unsigned short f2bf(float f) {
  union { float f; unsigned u; } v; v.f = f;
  unsigned u = v.u + 0x7fffu + ((v.u >> 16) & 1u);
  return (unsigned short)(u >> 16);
}
__device__ __forceinline__ float sigm(float x) {
  return __builtin_amdgcn_rcpf(1.0f + __expf(-x));
}
__device__ __forceinline__ float tanh_(float x) {
  return 1.0f - 2.0f * __builtin_amdgcn_rcpf(1.0f + __expf(2.0f * x));
}

// ---------------- prep: Wih emb-part (both dirs) -> frag bf16 [128 nt2][10 ks][64 l][8]
__global__ void prep_wih(const float* __restrict__ wf, const float* __restrict__ wb,
                         unsigned short* __restrict__ out) {
  int idx = blockIdx.x * 256 + threadIdx.x;           // [0, 81920)
  if (idx >= 128 * 10 * 64) return;
  int l = idx & 63, t2 = idx >> 6;
  int ks = t2 % 10, nt2 = t2 / 10;
  int n = nt2 * 16 + (l & 15), g = l >> 4;
  unsigned short* dst = out + (size_t)idx * 8;
#pragma unroll
  for (int i = 0; i < 8; ++i) {
    int k = ks * 32 + KOFF(g, i);
    float v = 0.f;
    if (k < 300) v = (n < 1024) ? wf[n * 303 + k] : wb[(n - 1024) * 303 + k];  // feat cols excluded
    dst[i] = f2bf(v);
  }
}

// ---------------- prep: Whh -> [2 d][64 nt][8 ks][64 l][8]
__global__ void prep_whh(const float* __restrict__ wf, const float* __restrict__ wb,
                         unsigned short* __restrict__ out) {
  int idx = blockIdx.x * 256 + threadIdx.x;           // [0, 65536)
  int l = idx & 63, t2 = idx >> 6;
  int ks = t2 & 7, t3 = t2 >> 3;
  int nt = t3 & 63, d = t3 >> 6;
  const float* w = d ? wb : wf;
  int n = nt * 16 + (l & 15), g = l >> 4;
  unsigned short* dst = out + (size_t)idx * 8;
#pragma unroll
  for (int i = 0; i < 8; ++i) {
    int k = ks * 32 + KOFF(g, i);
    dst[i] = f2bf(w[n * 256 + k]);
  }
}

// ---------------- prep: Wfc -> [3 nt][16 ks][64 l][8]
__global__ void prep_wfc(const float* __restrict__ wfc, unsigned short* __restrict__ out) {
  int idx = blockIdx.x * 256 + threadIdx.x;           // [0, 3072)
  if (idx >= 3 * 16 * 64) return;
  int l = idx & 63, t2 = idx >> 6;
  int ks = t2 & 15, nt = t2 >> 4;
  int n = nt * 16 + (l & 15), g = l >> 4;
  unsigned short* dst = out + (size_t)idx * 8;
#pragma unroll
  for (int i = 0; i < 8; ++i) {
    int k = ks * 32 + KOFF(g, i);
    dst[i] = f2bf(n < 39 ? wfc[n * 512 + k] : 0.f);
  }
}

// ---------------- prep: combined bias (f32) + fp32 feat-columns of Wih [2048][3]
__global__ void prep_bias(const float* bihf, const float* bhhf, const float* bihb,
                          const float* bhhb, const float* wihf, const float* wihb,
                          float* bias, float* wfeat) {
  int i = blockIdx.x * 256 + threadIdx.x;
  if (i >= 2048) return;
  int n = i & 1023;
  if (i < 1024) bias[i] = bihf[n] + bhhf[n];
  else          bias[i] = bihb[n] + bhhb[n];
  const float* w = (i < 1024) ? wihf : wihb;
#pragma unroll
  for (int j = 0; j < 3; ++j) wfeat[i * 3 + j] = w[n * 303 + 300 + j];
}

// ---------------- build inputs chunk (emb only): rows tl*256+b, t = t0+tl
__global__ void build_inputs(const int* __restrict__ x, const float* __restrict__ preW,
                             unsigned short* __restrict__ out, int t0, int Tc) {
  int idx = blockIdx.x * 256 + threadIdx.x;
  if (idx >= Tc * 256 * DIN_PAD) return;
  int row = idx / DIN_PAD, k = idx - row * DIN_PAD;
  int t = t0 + (row >> 8), b = row & 255;
  float v = 0.f;
  if (k < 300) {
    int tok = x[b * 800 + t];                     // x[b][0][t]
    v = preW[tok * 300 + k];
  }
  out[idx] = f2bf(v);
}

// ---------------- proj chunk (one dir): fp32 xp[tl][n(1024)][batch(256)]
// xp = emb@WihT (bf16 MFMA) + bias + fp32 feats@Wfeat
__global__ __launch_bounds__(256) void proj_gemm(const unsigned short* __restrict__ inp,
                                                 const unsigned short* __restrict__ wihc,
                                                 const float* __restrict__ biasc,
                                                 const float* __restrict__ wfeat,
                                                 const int* __restrict__ x,
                                                 float* __restrict__ xp,
                                                 int d, int Tc, int t0) {
  int nTile = blockIdx.x;                 // 0..7 (n within dir)
  int mTile = blockIdx.y;                 // 0..2*Tc-1
  int tl = mTile >> 1, b0 = (mTile & 1) * 128;
  int t = t0 + tl;
  int w = threadIdx.x >> 6, l = threadIdx.x & 63;
  int g = l >> 4, c = l & 15;
  float4v acc[2][8];
#pragma unroll
  for (int ms = 0; ms < 2; ++ms)
#pragma unroll
    for (int f = 0; f < 8; ++f) acc[ms][f] = (float4v){0.f, 0.f, 0.f, 0.f};

  for (int ks = 0; ks < 10; ++ks) {
    short8 a[2];
#pragma unroll
    for (int ms = 0; ms < 2; ++ms) {
      int rowA = tl * 256 + b0 + w * 32 + ms * 16 + c;
      const unsigned short* p = inp + (size_t)rowA * DIN_PAD + ks * 32 + 4 * g;
      union { short8 v; U2 q[2]; } A;
      A.q[0] = *(const U2*)p;
      A.q[1] = *(const U2*)(p + 16);
      a[ms] = A.v;
    }
#pragma unroll
    for (int f = 0; f < 8; ++f) {
      int nt2 = d * 64 + nTile * 8 + f;
      short8 bb = *(const short8*)(wihc + ((size_t)(nt2 * 10 + ks) * 64 + l) * 8);
      acc[0][f] = __builtin_amdgcn_mfma_f32_16x16x32_bf16(a[0], bb, acc[0][f], 0, 0, 0);
      acc[1][f] = __builtin_amdgcn_mfma_f32_16x16x32_bf16(a[1], bb, acc[1][f], 0, 0, 0);
    }
  }
#pragma unroll
  for (int ms = 0; ms < 2; ++ms) {
    float ft[4][3];
#pragma unroll
    for (int r = 0; r < 4; ++r) {
      int b = b0 + w * 32 + ms * 16 + 4 * g + r;
#pragma unroll
      for (int j = 0; j < 3; ++j)
        ft[r][j] = (float)x[b * 800 + (1 + j) * 200 + t];   // exact ints in fp32
    }
#pragma unroll
    for (int f = 0; f < 8; ++f) {
      int n = nTile * 128 + f * 16 + c;        // within dir [0,1024)
      float bias = biasc[d * 1024 + n];
      const float* wfp = wfeat + (size_t)(d * 1024 + n) * 3;
      float w0 = wfp[0], w1 = wfp[1], w2 = wfp[2];
      float4v res;
#pragma unroll
      for (int r = 0; r < 4; ++r)
        res[r] = acc[ms][f][r] + bias + ft[r][0] * w0 + ft[r][1] * w1 + ft[r][2] * w2;
      size_t o = ((size_t)tl * 1024 + n) * 256 + (b0 + w * 32 + ms * 16 + 4 * g);
      *(float4v*)(xp + o) = res;
    }
  }
}

// ---------------- LSTM recurrence: 256 WGs x 256 thr (1/CU).
// WG = (slice(8), d(2), btile(16)): computes h[btile rows][slice*32 dims].
// Wave w: p=w&1 (16-dim half), qh=w>>1 (gate pair). 2 n-tiles of weights in
// VGPRs (64 regs, no pressure). Cross-WG h-exchange via hout + agent-scope
// release/acquire flags (one per (d,btile,t)).
__global__ __launch_bounds__(256, 1) void lstm_rec(const float* __restrict__ xpf,
                                                   const float* __restrict__ xpb,
                                                   const unsigned short* __restrict__ whhf,
                                                   unsigned short* __restrict__ hout,
                                                   float* __restrict__ cstate,
                                                   int* __restrict__ flags,
                                                   int t0f, int t0b, int Tc, int initFlag) {
  int wgid = blockIdx.x;
  int slice = wgid >> 5, d = (wgid >> 4) & 1, btile = wgid & 15;
  int tid = threadIdx.x, w = tid >> 6, l = tid & 63;
  int g = l >> 4, c = l & 15;
  int p = w & 1, qh = w >> 1;
  __shared__ __align__(16) float red[2][2][64][4];   // gate g,o partials from qh=1 waves

  // weights: 2 n-tiles (gates qh*2, qh*2+1; parity p) x 8 ks = 64 VGPRs
  short8 Bres[2][8];
#pragma unroll
  for (int j = 0; j < 2; ++j) {
    int q = qh * 2 + j;
    int nt = q * 16 + slice * 2 + p;
#pragma unroll
    for (int ks = 0; ks < 8; ++ks)
      Bres[j][ks] = *(const short8*)(whhf + ((size_t)((d * 64 + nt) * 8 + ks) * 64 + l) * 8);
  }

  float4v cst = (float4v){0.f, 0.f, 0.f, 0.f};
  if (!initFlag && tid < 128) cst = *(const float4v*)&cstate[((size_t)wgid * 128 + tid) * 4];

  const float* xp = d ? xpb : xpf;
  int t0 = d ? t0b : t0f;
  int fbase = (d * 16 + btile) * 200;

  for (int s = 0; s < Tc; ++s) {
    int tl = d ? (Tc - 1 - s) : s;
    int t = t0 + tl;
    int t_prev = d ? (t + 1) : (t - 1);
    bool first = (initFlag && s == 0);

    // xq is h-independent: load before the poll to hide latency (qh0 waves only)
    float4v xq[4];
    if (qh == 0) {
      const float* xb2 = xp + ((size_t)tl * 1024 + slice * 32 + p * 16 + c) * 256 + btile * 16 + 4 * g;
#pragma unroll
      for (int q2 = 0; q2 < 4; ++q2) xq[q2] = *(const float4v*)(xb2 + (size_t)q2 * 65536);
    }

    if (!first) {
      // all lanes spin uniformly (coalesces to one load/wave); acquire invalidates caches
      while (__hip_atomic_load(&flags[fbase + t_prev], __ATOMIC_ACQUIRE,
                               __HIP_MEMORY_SCOPE_AGENT) < 8) {
        __builtin_amdgcn_s_sleep(1);
      }
    }

    // load h(t_prev) A-fragments from hout (fresh post-acquire)
    short8 hA[8];
    if (first) {
#pragma unroll
      for (int ks = 0; ks < 8; ++ks) hA[ks] = (short8){0, 0, 0, 0, 0, 0, 0, 0};
    } else {
      const unsigned short* hp = hout + ((size_t)(t_prev * 256 + btile * 16 + c)) * 512 + d * 256 + 4 * g;
#pragma unroll
      for (int ks = 0; ks < 8; ++ks) {
        union { short8 v; U2 q2[2]; } A;
        A.q2[0] = *(const U2*)(hp + ks * 32);
        A.q2[1] = *(const U2*)(hp + ks * 32 + 16);
        hA[ks] = A.v;
      }
    }

    float4v acc[2];
    acc[0] = (float4v){0.f, 0.f, 0.f, 0.f};
    acc[1] = (float4v){0.f, 0.f, 0.f, 0.f};
#pragma unroll
    for (int ks = 0; ks < 8; ++ks) {
      acc[0] = __builtin_amdgcn_mfma_f32_16x16x32_bf16(hA[ks], Bres[0][ks], acc[0], 0, 0, 0);
      acc[1] = __builtin_amdgcn_mfma_f32_16x16x32_bf16(hA[ks], Bres[1][ks], acc[1], 0, 0, 0);
    }

    if (qh == 1) {   // gates g(2), o(3) -> hand partials to qh0 waves
      *(float4v*)&red[p][0][l][0] = acc[0];
      *(float4v*)&red[p][1][l][0] = acc[1];
    }
    __syncthreads();

    if (qh == 0) {   // gates i(0), f(1) local; g,o from red; cell update
      float4v gacc = *(const float4v*)&red[p][0][l][0];
      float4v oacc = *(const float4v*)&red[p][1][l][0];
      int hdim = slice * 32 + p * 16 + c;
      unsigned short* hw = hout + ((size_t)(t * 256 + btile * 16 + 4 * g)) * 512 + d * 256 + hdim;
#pragma unroll
      for (int r = 0; r < 4; ++r) {
        float iv = sigm(acc[0][r] + xq[0][r]);
        float fv = sigm(acc[1][r] + xq[1][r]);
        float gv = tanh_(gacc[r] + xq[2][r]);
        float ov = sigm(oacc[r] + xq[3][r]);
        float cc = fv * cst[r] + iv * gv;
        cst[r] = cc;
        hw[(size_t)r * 512] = f2bf(ov * tanh_(cc));
      }
      __threadfence();   // make h stores agent-visible before the flag bump
    }
    __syncthreads();     // qh0 fences done; red consumed before next-iter overwrite
    if (tid == 0)
      __hip_atomic_fetch_add(&flags[fbase + t], 1, __ATOMIC_RELEASE, __HIP_MEMORY_SCOPE_AGENT);
  }

  if (tid < 128) *(float4v*)&cstate[((size_t)wgid * 128 + tid) * 4] = cst;
}

// ---------------- FC: out = [hf|hb] @ WfcT + bfc
__global__ __launch_bounds__(256) void fc_out(const unsigned short* __restrict__ hout,
                                              const unsigned short* __restrict__ wfcf,
                                              const float* __restrict__ bfc,
                                              float* __restrict__ out) {
  int bq = blockIdx.x;        // 0..3
  int t  = blockIdx.y;        // 0..199
  int w = threadIdx.x >> 6, l = threadIdx.x & 63;
  int g = l >> 4, c = l & 15;
  int b0 = bq * 64 + w * 16;
  float4v acc[3];
#pragma unroll
  for (int nt = 0; nt < 3; ++nt) acc[nt] = (float4v){0.f, 0.f, 0.f, 0.f};
  for (int ks = 0; ks < 16; ++ks) {
    const unsigned short* p = hout + (size_t)(t * 256 + b0 + c) * 512 + ks * 32 + 4 * g;
    union { short8 v; U2 q[2]; } A;
    A.q[0] = *(const U2*)p;
    A.q[1] = *(const U2*)(p + 16);
#pragma unroll
    for (int nt = 0; nt < 3; ++nt) {
      short8 bb = *(const short8*)(wfcf + ((size_t)(nt * 16 + ks) * 64 + l) * 8);
      acc[nt] = __builtin_amdgcn_mfma_f32_16x16x32_bf16(A.v, bb, acc[nt], 0, 0, 0);
    }
  }
#pragma unroll
  for (int nt = 0; nt < 3; ++nt) {
    int j = nt * 16 + c;
    if (j < 39) {
      float bias = bfc[j];
#pragma unroll
      for (int r = 0; r < 4; ++r) {
        int b = b0 + 4 * g + r;
        out[(size_t)(b * 200 + t) * 39 + j] = acc[nt][r] + bias;
      }
    }
  }
}

extern "C" void kernel_launch(void* const* d_in, const int* in_sizes, int n_in,
                              void* d_out, int out_size, void* d_ws, size_t ws_size,
                              hipStream_t stream) {
  (void)in_sizes; (void)n_in; (void)out_size;
  const int*   x     = (const int*)d_in[0];
  const float* preW  = (const float*)d_in[1];
  const float* wih_f = (const float*)d_in[2];
  const float* whh_f = (const float*)d_in[3];
  const float* bih_f = (const float*)d_in[4];
  const float* bhh_f = (const float*)d_in[5];
  const float* wih_b = (const float*)d_in[6];
  const float* whh_b = (const float*)d_in[7];
  const float* bih_b = (const float*)d_in[8];
  const float* bhh_b = (const float*)d_in[9];
  const float* wfc   = (const float*)d_in[10];
  const float* bfc   = (const float*)d_in[11];
  float* out = (float*)d_out;
  char* ws = (char*)d_ws;

  size_t off = 0;
  auto alloc = [&](size_t bytes) -> char* {
    char* p = ws + off;
    off = (off + bytes + 255) & ~(size_t)255;
    return p;
  };
  unsigned short* wihc   = (unsigned short*)alloc(1310720);
  unsigned short* whhf   = (unsigned short*)alloc(1048576);
  unsigned short* wfcf   = (unsigned short*)alloc(49152);
  float*          biasc  = (float*)alloc(8192);
  float*          wfeat  = (float*)alloc(24576);
  float*          cstate = (float*)alloc(524288);
  int*            flags  = (int*)alloc(25600);
  unsigned short* hout   = (unsigned short*)alloc(52428800);
  size_t fixedEnd = off;

  // largest chunk fitting ws_size: inp (Tc*163840 B) + 2 fp32 xp (Tc*1048576 B each)
  static const int tcs[] = {100, 50, 25, 20, 10, 8, 5};
  int Tc = 5;
  for (int i = 0; i < 7; ++i) {
    size_t need = fixedEnd + (size_t)tcs[i] * 163840 + 256 + 2 * ((size_t)tcs[i] * 1048576 + 256);
    if (need <= ws_size) { Tc = tcs[i]; break; }
  }
  unsigned short* inp = (unsigned short*)alloc((size_t)Tc * 163840);
  float* xpf = (float*)alloc((size_t)Tc * 1048576);
  float* xpb = (float*)alloc((size_t)Tc * 1048576);

  hipMemsetAsync(flags, 0, 6400 * sizeof(int), stream);
  hipLaunchKernelGGL(prep_wih,  dim3(320), dim3(256), 0, stream, wih_f, wih_b, wihc);
  hipLaunchKernelGGL(prep_whh,  dim3(256), dim3(256), 0, stream, whh_f, whh_b, whhf);
  hipLaunchKernelGGL(prep_wfc,  dim3(12),  dim3(256), 0, stream, wfc, wfcf);
  hipLaunchKernelGGL(prep_bias, dim3(8),   dim3(256), 0, stream, bih_f, bhh_f, bih_b, bhh_b,
                     wih_f, wih_b, biasc, wfeat);

  int NC = L_SEQ / Tc;
  int bgrid = (Tc * 256 * DIN_PAD + 255) / 256;
  for (int k = 0; k < NC; ++k) {
    int t0f = k * Tc;
    int t0b = L_SEQ - (k + 1) * Tc;
    hipLaunchKernelGGL(build_inputs, dim3(bgrid), dim3(256), 0, stream, x, preW, inp, t0f, Tc);
    hipLaunchKernelGGL(proj_gemm, dim3(8, 2 * Tc), dim3(256), 0, stream, inp, wihc, biasc,
                       wfeat, x, xpf, 0, Tc, t0f);
    hipLaunchKernelGGL(build_inputs, dim3(bgrid), dim3(256), 0, stream, x, preW, inp, t0b, Tc);
    hipLaunchKernelGGL(proj_gemm, dim3(8, 2 * Tc), dim3(256), 0, stream, inp, wihc, biasc,
                       wfeat, x, xpb, 1, Tc, t0b);
    hipLaunchKernelGGL(lstm_rec, dim3(256), dim3(256), 0, stream, xpf, xpb, whhf, hout,
                       cstate, flags, t0f, t0b, Tc, k == 0 ? 1 : 0);
  }
  hipLaunchKernelGGL(fc_out, dim3(4, 200), dim3(256), 0, stream, hout, wfcf, bfc, out);
}

// Round 7
// 1417.838 us; speedup vs baseline: 4.9231x; 4.9231x over previous
//
#include <hip/hip_runtime.h>
#include <hip/hip_bf16.h>
#include <stdint.h>

#define L_SEQ 200
#define DIN_PAD 320   // 303 padded to 320; only first 300 (emb) nonzero in bf16 path

using short8  = __attribute__((ext_vector_type(8))) short;
using float4v = __attribute__((ext_vector_type(4))) float;

struct U2 { unsigned x, y; };

// k-slot mapping within a 32-wide K slice for mfma_f32_16x16x32_bf16 operands.
// Applied identically to A and B operands, so correctness is invariant to the
// exact hw intra-slice permutation (A/B layouts are symmetric).
#define KOFF(g,i) (((i)&3) + 4*(g) + 16*((i)>>2))

__device__ __forceinline__ unsigned short f2bf(float f) {
  union { float f; unsigned u; } v; v.f = f;
  unsigned u = v.u + 0x7fffu + ((v.u >> 16) & 1u);
  return (unsigned short)(u >> 16);
}
__device__ __forceinline__ float sigm(float x) {
  return __builtin_amdgcn_rcpf(1.0f + __expf(-x));
}
__device__ __forceinline__ float tanh_(float x) {
  return 1.0f - 2.0f * __builtin_amdgcn_rcpf(1.0f + __expf(2.0f * x));
}

// ---------------- prep: Wih emb-part (both dirs) -> frag bf16 [128 nt2][10 ks][64 l][8]
__global__ void prep_wih(const float* __restrict__ wf, const float* __restrict__ wb,
                         unsigned short* __restrict__ out) {
  int idx = blockIdx.x * 256 + threadIdx.x;           // [0, 81920)
  if (idx >= 128 * 10 * 64) return;
  int l = idx & 63, t2 = idx >> 6;
  int ks = t2 % 10, nt2 = t2 / 10;
  int n = nt2 * 16 + (l & 15), g = l >> 4;
  unsigned short* dst = out + (size_t)idx * 8;
#pragma unroll
  for (int i = 0; i < 8; ++i) {
    int k = ks * 32 + KOFF(g, i);
    float v = 0.f;
    if (k < 300) v = (n < 1024) ? wf[n * 303 + k] : wb[(n - 1024) * 303 + k];  // feat cols excluded
    dst[i] = f2bf(v);
  }
}

// ---------------- prep: Whh -> [2 d][64 nt][8 ks][64 l][8]
__global__ void prep_whh(const float* __restrict__ wf, const float* __restrict__ wb,
                         unsigned short* __restrict__ out) {
  int idx = blockIdx.x * 256 + threadIdx.x;           // [0, 65536)
  int l = idx & 63, t2 = idx >> 6;
  int ks = t2 & 7, t3 = t2 >> 3;
  int nt = t3 & 63, d = t3 >> 6;
  const float* w = d ? wb : wf;
  int n = nt * 16 + (l & 15), g = l >> 4;
  unsigned short* dst = out + (size_t)idx * 8;
#pragma unroll
  for (int i = 0; i < 8; ++i) {
    int k = ks * 32 + KOFF(g, i);
    dst[i] = f2bf(w[n * 256 + k]);
  }
}

// ---------------- prep: Wfc -> [3 nt][16 ks][64 l][8]
__global__ void prep_wfc(const float* __restrict__ wfc, unsigned short* __restrict__ out) {
  int idx = blockIdx.x * 256 + threadIdx.x;           // [0, 3072)
  if (idx >= 3 * 16 * 64) return;
  int l = idx & 63, t2 = idx >> 6;
  int ks = t2 & 15, nt = t2 >> 4;
  int n = nt * 16 + (l & 15), g = l >> 4;
  unsigned short* dst = out + (size_t)idx * 8;
#pragma unroll
  for (int i = 0; i < 8; ++i) {
    int k = ks * 32 + KOFF(g, i);
    dst[i] = f2bf(n < 39 ? wfc[n * 512 + k] : 0.f);
  }
}

// ---------------- prep: combined bias (f32) + fp32 feat-columns of Wih [2048][3]
__global__ void prep_bias(const float* bihf, const float* bhhf, const float* bihb,
                          const float* bhhb, const float* wihf, const float* wihb,
                          float* bias, float* wfeat) {
  int i = blockIdx.x * 256 + threadIdx.x;
  if (i >= 2048) return;
  int n = i & 1023;
  if (i < 1024) bias[i] = bihf[n] + bhhf[n];
  else          bias[i] = bihb[n] + bhhb[n];
  const float* w = (i < 1024) ? wihf : wihb;
#pragma unroll
  for (int j = 0; j < 3; ++j) wfeat[i * 3 + j] = w[n * 303 + 300 + j];
}

// ---------------- build inputs chunk (emb only): rows tl*256+b, t = t0+tl
__global__ void build_inputs(const int* __restrict__ x, const float* __restrict__ preW,
                             unsigned short* __restrict__ out, int t0, int Tc) {
  int idx = blockIdx.x * 256 + threadIdx.x;
  if (idx >= Tc * 256 * DIN_PAD) return;
  int row = idx / DIN_PAD, k = idx - row * DIN_PAD;
  int t = t0 + (row >> 8), b = row & 255;
  float v = 0.f;
  if (k < 300) {
    int tok = x[b * 800 + t];                     // x[b][0][t]
    v = preW[tok * 300 + k];
  }
  out[idx] = f2bf(v);
}

// ---------------- proj chunk (one dir): fp32 xp[(rt*Tc+tl)][w3][ff][l][4]
// xp = emb@WihT (bf16 MFMA) + bias + fp32 feats@Wfeat
__global__ __launch_bounds__(256) void proj_gemm(const unsigned short* __restrict__ inp,
                                                 const unsigned short* __restrict__ wihc,
                                                 const float* __restrict__ biasc,
                                                 const float* __restrict__ wfeat,
                                                 const int* __restrict__ x,
                                                 float* __restrict__ xp,
                                                 int d, int Tc, int t0) {
  int nTile = blockIdx.x;                 // 0..7 (n within dir)
  int mTile = blockIdx.y;                 // 0..2*Tc-1
  int tl = mTile >> 1, b0 = (mTile & 1) * 128;
  int t = t0 + tl;
  int w = threadIdx.x >> 6, l = threadIdx.x & 63;
  int g = l >> 4, c = l & 15;
  float4v acc[2][8];
#pragma unroll
  for (int ms = 0; ms < 2; ++ms)
#pragma unroll
    for (int f = 0; f < 8; ++f) acc[ms][f] = (float4v){0.f, 0.f, 0.f, 0.f};

  for (int ks = 0; ks < 10; ++ks) {
    short8 a[2];
#pragma unroll
    for (int ms = 0; ms < 2; ++ms) {
      int rowA = tl * 256 + b0 + w * 32 + ms * 16 + c;
      const unsigned short* p = inp + (size_t)rowA * DIN_PAD + ks * 32 + 4 * g;
      union { short8 v; U2 q[2]; } A;
      A.q[0] = *(const U2*)p;
      A.q[1] = *(const U2*)(p + 16);
      a[ms] = A.v;
    }
#pragma unroll
    for (int f = 0; f < 8; ++f) {
      int nt2 = d * 64 + nTile * 8 + f;
      short8 bb = *(const short8*)(wihc + ((size_t)(nt2 * 10 + ks) * 64 + l) * 8);
      acc[0][f] = __builtin_amdgcn_mfma_f32_16x16x32_bf16(a[0], bb, acc[0][f], 0, 0, 0);
      acc[1][f] = __builtin_amdgcn_mfma_f32_16x16x32_bf16(a[1], bb, acc[1][f], 0, 0, 0);
    }
  }
#pragma unroll
  for (int ms = 0; ms < 2; ++ms) {
    int rt = (b0 >> 4) + w * 2 + ms;
    float ft[4][3];
#pragma unroll
    for (int r = 0; r < 4; ++r) {
      int b = b0 + w * 32 + ms * 16 + 4 * g + r;
#pragma unroll
      for (int j = 0; j < 3; ++j)
        ft[r][j] = (float)x[b * 800 + (1 + j) * 200 + t];   // exact ints in fp32
    }
#pragma unroll
    for (int f = 0; f < 8; ++f) {
      int n = nTile * 128 + f * 16 + c;        // within dir [0,1024)
      float bias = biasc[d * 1024 + n];
      const float* wfp = wfeat + (size_t)(d * 1024 + n) * 3;
      float w0 = wfp[0], w1 = wfp[1], w2 = wfp[2];
      int q = n >> 8, w3 = (n >> 5) & 7, p = (n >> 4) & 1;
      int ff = q * 2 + p;
      size_t o = ((((size_t)(rt * Tc + tl) * 8 + w3) * 8 + ff) * 64 + l) * 4;
      float4v res;
#pragma unroll
      for (int r = 0; r < 4; ++r)
        res[r] = acc[ms][f][r] + bias + ft[r][0] * w0 + ft[r][1] * w1 + ft[r][2] * w2;
      *(float4v*)(xp + o) = res;
    }
  }
}

// ---------------- LSTM recurrence chunk. 32 WGs = 16 batch-tiles x 2 dirs, 1 WG/CU.
// Whh split across all on-CU storage: gates i,f (ff0-3) in 128 VGPRs/wave
// (amdgpu_waves_per_eu(2,2) -> 256-reg budget, allocator can't target 4 waves);
// gate g (ff4,5) in 128 KB LDS (loaded once, read 200x); gate o (ff6,7)
// streamed from L2 with rotating 3-deep prefetch. hA single-live per ks.
__global__ __launch_bounds__(512) __attribute__((amdgpu_waves_per_eu(2, 2)))
void lstm_rec(const float* __restrict__ xpf,
              const float* __restrict__ xpb,
              const unsigned short* __restrict__ whhf,
              unsigned short* __restrict__ hout,
              unsigned short* __restrict__ hstate,
              float* __restrict__ cstate,
              int t0f, int t0b, int Tc, int initFlag) {
  extern __shared__ __align__(16) unsigned short smem[];
  unsigned short* hf   = smem;          // [8 ks][64 l][8] = 8 KB
  unsigned short* ldsW = smem + 4096;   // [2 j][8 ks][512 tid][8] = 128 KB

  int d = blockIdx.x & 1, rt = blockIdx.x >> 1;
  int tid = threadIdx.x, w = tid >> 6, l = tid & 63;
  int g = l >> 4, c = l & 15;

  float4v cst[2];
  unsigned short* hs = hstate + (size_t)(d * 16 + rt) * 4096;
  float* cs = cstate + ((size_t)(d * 16 + rt) * 512 + tid) * 8;
  if (initFlag) {
    for (int i = tid; i < 4096; i += 512) hf[i] = 0;
    cst[0] = (float4v){0.f, 0.f, 0.f, 0.f};
    cst[1] = (float4v){0.f, 0.f, 0.f, 0.f};
  } else {
    for (int i = tid; i < 4096; i += 512) hf[i] = hs[i];
#pragma unroll
    for (int p = 0; p < 2; ++p)
#pragma unroll
      for (int r = 0; r < 4; ++r) cst[p][r] = cs[p * 4 + r];
  }

  // LDS-resident weights: gate g (q=2), parity j -> nt = 32 + w*2 + j
#pragma unroll
  for (int j = 0; j < 2; ++j) {
    int nt = 32 + w * 2 + j;
#pragma unroll
    for (int ks = 0; ks < 8; ++ks) {
      short8 v = *(const short8*)(whhf + ((size_t)((d * 64 + nt) * 8 + ks) * 64 + l) * 8);
      *(short8*)&ldsW[((size_t)(j * 8 + ks) * 512 + tid) * 8] = v;
    }
  }

  // register-resident: gates i (q=0), f (q=1): ff=0..3, nt = (ff>>1)*16 + w*2 + (ff&1)
  short8 Bres[4][8];
#pragma unroll
  for (int f = 0; f < 4; ++f) {
    int nt = (f >> 1) * 16 + w * 2 + (f & 1);
#pragma unroll
    for (int ks = 0; ks < 8; ++ks)
      Bres[f][ks] = *(const short8*)(whhf + ((size_t)((d * 64 + nt) * 8 + ks) * 64 + l) * 8);
  }

  // streamed: gate o (q=3): ff=6,7 -> nt = 48 + w*2 + j  (L2-resident, same addrs every step)
  const unsigned short* so0 = whhf + ((size_t)((d * 64 + 48 + w * 2 + 0) * 8) * 64 + l) * 8;
  const unsigned short* so1 = whhf + ((size_t)((d * 64 + 48 + w * 2 + 1) * 8) * 64 + l) * 8;

  const float* xp = d ? xpb : xpf;
  int t0 = d ? t0b : t0f;
  size_t xb = (size_t)rt * Tc * 16384 + (size_t)w * 2048 + (size_t)l * 4;
  __syncthreads();

  for (int s = 0; s < Tc; ++s) {
    int tl = d ? (Tc - 1 - s) : s;
    int t = t0 + tl;

    // xq issued first (HBM latency hides under the whole MFMA phase)
    size_t xt = xb + (size_t)tl * 16384;
    float4v xq[8];
#pragma unroll
    for (int f = 0; f < 8; ++f) xq[f] = *(const float4v*)(xp + xt + f * 256);

    // stream prologue: 3-deep rotating prefetch of gate-o fragments
    short8 sa[3], sb[3];
#pragma unroll
    for (int kk = 0; kk < 3; ++kk) {
      sa[kk] = *(const short8*)(so0 + (size_t)kk * 512);
      sb[kk] = *(const short8*)(so1 + (size_t)kk * 512);
    }

    float4v acc[8];
#pragma unroll
    for (int f = 0; f < 8; ++f) acc[f] = (float4v){0.f, 0.f, 0.f, 0.f};

#pragma unroll
    for (int ks = 0; ks < 8; ++ks) {
      short8 hAk = *(const short8*)&hf[ks * 512 + l * 8];
      short8 lw0 = *(const short8*)&ldsW[((size_t)(ks) * 512 + tid) * 8];
      short8 lw1 = *(const short8*)&ldsW[((size_t)(8 + ks) * 512 + tid) * 8];
      acc[0] = __builtin_amdgcn_mfma_f32_16x16x32_bf16(hAk, Bres[0][ks], acc[0], 0, 0, 0);
      acc[1] = __builtin_amdgcn_mfma_f32_16x16x32_bf16(hAk, Bres[1][ks], acc[1], 0, 0, 0);
      acc[2] = __builtin_amdgcn_mfma_f32_16x16x32_bf16(hAk, Bres[2][ks], acc[2], 0, 0, 0);
      acc[3] = __builtin_amdgcn_mfma_f32_16x16x32_bf16(hAk, Bres[3][ks], acc[3], 0, 0, 0);
      acc[4] = __builtin_amdgcn_mfma_f32_16x16x32_bf16(hAk, lw0, acc[4], 0, 0, 0);
      acc[5] = __builtin_amdgcn_mfma_f32_16x16x32_bf16(hAk, lw1, acc[5], 0, 0, 0);
      acc[6] = __builtin_amdgcn_mfma_f32_16x16x32_bf16(hAk, sa[ks % 3], acc[6], 0, 0, 0);
      acc[7] = __builtin_amdgcn_mfma_f32_16x16x32_bf16(hAk, sb[ks % 3], acc[7], 0, 0, 0);
      if (ks < 5) {
        sa[ks % 3] = *(const short8*)(so0 + (size_t)(ks + 3) * 512);
        sb[ks % 3] = *(const short8*)(so1 + (size_t)(ks + 3) * 512);
      }
    }
    __syncthreads();   // all hf reads of this step done before anyone writes new h

#pragma unroll
    for (int f = 0; f < 8; ++f) acc[f] = acc[f] + xq[f];

    // cell: ff = q*2+p, q: 0=i 1=f 2=g 3=o; lane holds batch m=4g+r, h-dim p*16+c
    int hrow = t * 256 + rt * 16;
#pragma unroll
    for (int p = 0; p < 2; ++p) {
#pragma unroll
      for (int r = 0; r < 4; ++r) {
        float iv = sigm(acc[0 + p][r]);
        float fv = sigm(acc[2 + p][r]);
        float gv = tanh_(acc[4 + p][r]);
        float ov = sigm(acc[6 + p][r]);
        float cc = fv * cst[p][r] + iv * gv;
        cst[p][r] = cc;
        float hh = ov * tanh_(cc);
        unsigned short hb = f2bf(hh);
        int m = 4 * g + r;
        hout[(size_t)(hrow + m) * 512 + d * 256 + w * 32 + p * 16 + c] = hb;
        hf[w * 512 + (m + 16 * (c >> 2)) * 8 + 4 * p + (c & 3)] = hb;  // inverse KOFF
      }
    }
    __syncthreads();
  }

  // persist state for next chunk
  for (int i = tid; i < 4096; i += 512) hs[i] = hf[i];
#pragma unroll
  for (int p = 0; p < 2; ++p)
#pragma unroll
    for (int r = 0; r < 4; ++r) cs[p * 4 + r] = cst[p][r];
}

// ---------------- FC: out = [hf|hb] @ WfcT + bfc
__global__ __launch_bounds__(256) void fc_out(const unsigned short* __restrict__ hout,
                                              const unsigned short* __restrict__ wfcf,
                                              const float* __restrict__ bfc,
                                              float* __restrict__ out) {
  int bq = blockIdx.x;        // 0..3
  int t  = blockIdx.y;        // 0..199
  int w = threadIdx.x >> 6, l = threadIdx.x & 63;
  int g = l >> 4, c = l & 15;
  int b0 = bq * 64 + w * 16;
  float4v acc[3];
#pragma unroll
  for (int nt = 0; nt < 3; ++nt) acc[nt] = (float4v){0.f, 0.f, 0.f, 0.f};
  for (int ks = 0; ks < 16; ++ks) {
    const unsigned short* p = hout + (size_t)(t * 256 + b0 + c) * 512 + ks * 32 + 4 * g;
    union { short8 v; U2 q[2]; } A;
    A.q[0] = *(const U2*)p;
    A.q[1] = *(const U2*)(p + 16);
#pragma unroll
    for (int nt = 0; nt < 3; ++nt) {
      short8 bb = *(const short8*)(wfcf + ((size_t)(nt * 16 + ks) * 64 + l) * 8);
      acc[nt] = __builtin_amdgcn_mfma_f32_16x16x32_bf16(A.v, bb, acc[nt], 0, 0, 0);
    }
  }
#pragma unroll
  for (int nt = 0; nt < 3; ++nt) {
    int j = nt * 16 + c;
    if (j < 39) {
      float bias = bfc[j];
#pragma unroll
      for (int r = 0; r < 4; ++r) {
        int b = b0 + 4 * g + r;
        out[(size_t)(b * 200 + t) * 39 + j] = acc[nt][r] + bias;
      }
    }
  }
}

extern "C" void kernel_launch(void* const* d_in, const int* in_sizes, int n_in,
                              void* d_out, int out_size, void* d_ws, size_t ws_size,
                              hipStream_t stream) {
  (void)in_sizes; (void)n_in; (void)out_size;
  const int*   x     = (const int*)d_in[0];
  const float* preW  = (const float*)d_in[1];
  const float* wih_f = (const float*)d_in[2];
  const float* whh_f = (const float*)d_in[3];
  const float* bih_f = (const float*)d_in[4];
  const float* bhh_f = (const float*)d_in[5];
  const float* wih_b = (const float*)d_in[6];
  const float* whh_b = (const float*)d_in[7];
  const float* bih_b = (const float*)d_in[8];
  const float* bhh_b = (const float*)d_in[9];
  const float* wfc   = (const float*)d_in[10];
  const float* bfc   = (const float*)d_in[11];
  float* out = (float*)d_out;
  char* ws = (char*)d_ws;

  size_t off = 0;
  auto alloc = [&](size_t bytes) -> char* {
    char* p = ws + off;
    off = (off + bytes + 255) & ~(size_t)255;
    return p;
  };
  unsigned short* wihc   = (unsigned short*)alloc(1310720);
  unsigned short* whhf   = (unsigned short*)alloc(1048576);
  unsigned short* wfcf   = (unsigned short*)alloc(49152);
  float*          biasc  = (float*)alloc(8192);
  float*          wfeat  = (float*)alloc(24576);
  unsigned short* hstate = (unsigned short*)alloc(262144);
  float*          cstate = (float*)alloc(524288);
  unsigned short* hout   = (unsigned short*)alloc(52428800);
  size_t fixedEnd = off;

  // largest chunk fitting ws_size: inp (Tc*163840 B) + 2 fp32 xp (Tc*1048576 B each)
  static const int tcs[] = {100, 50, 25, 20, 10, 8, 5};
  int Tc = 5;
  for (int i = 0; i < 7; ++i) {
    size_t need = fixedEnd + (size_t)tcs[i] * 163840 + 256 + 2 * ((size_t)tcs[i] * 1048576 + 256);
    if (need <= ws_size) { Tc = tcs[i]; break; }
  }
  unsigned short* inp = (unsigned short*)alloc((size_t)Tc * 163840);
  float* xpf = (float*)alloc((size_t)Tc * 1048576);
  float* xpb = (float*)alloc((size_t)Tc * 1048576);

  hipLaunchKernelGGL(prep_wih,  dim3(320), dim3(256), 0, stream, wih_f, wih_b, wihc);
  hipLaunchKernelGGL(prep_whh,  dim3(256), dim3(256), 0, stream, whh_f, whh_b, whhf);
  hipLaunchKernelGGL(prep_wfc,  dim3(12),  dim3(256), 0, stream, wfc, wfcf);
  hipLaunchKernelGGL(prep_bias, dim3(8),   dim3(256), 0, stream, bih_f, bhh_f, bih_b, bhh_b,
                     wih_f, wih_b, biasc, wfeat);

  int NC = L_SEQ / Tc;
  int bgrid = (Tc * 256 * DIN_PAD + 255) / 256;
  for (int k = 0; k < NC; ++k) {
    int t0f = k * Tc;
    int t0b = L_SEQ - (k + 1) * Tc;
    hipLaunchKernelGGL(build_inputs, dim3(bgrid), dim3(256), 0, stream, x, preW, inp, t0f, Tc);
    hipLaunchKernelGGL(proj_gemm, dim3(8, 2 * Tc), dim3(256), 0, stream, inp, wihc, biasc,
                       wfeat, x, xpf, 0, Tc, t0f);
    hipLaunchKernelGGL(build_inputs, dim3(bgrid), dim3(256), 0, stream, x, preW, inp, t0b, Tc);
    hipLaunchKernelGGL(proj_gemm, dim3(8, 2 * Tc), dim3(256), 0, stream, inp, wihc, biasc,
                       wfeat, x, xpb, 1, Tc, t0b);
    hipLaunchKernelGGL(lstm_rec, dim3(32), dim3(512), 139264, stream, xpf, xpb, whhf, hout,
                       hstate, cstate, t0f, t0b, Tc, k == 0 ? 1 : 0);
  }
  hipLaunchKernelGGL(fc_out, dim3(4, 200), dim3(256), 0, stream, hout, wfcf, bfc, out);
}